// Round 1
// baseline (258.056 us; speedup 1.0000x reference)
//
#include <hip/hip_runtime.h>

// out[b, i] = x[b, i] * kernel[i, i]
// B = 8192, N = 4096, fp32. Pure HBM-bandwidth problem: 128 MiB in + 128 MiB out.
// Floor for the scale work at measured streaming rate (~6.3 TB/s): ~43 us.
//
// This round: NO workspace usage, single fused kernel.
//   - Grid-stride step (2048 blocks x 256 thr = 524288) is a multiple of
//     N/4 = 1024, so each thread's float4-column-group (t & 1023) is
//     loop-invariant -> its 4 diagonal scales are loaded ONCE into registers,
//     straight from the kernel matrix (stride N+1). Those 4096 cache lines
//     are L2-resident after first touch and broadcast to every thread:
//     ~1 MiB of extra HBM first-touch vs. the 16 KiB staged copy -> noise.
//   - x / out are streamed once -> non-temporal loads/stores.

#define DK_N 4096
#define DK_N4 (DK_N / 4)

// Native vector type: __builtin_nontemporal_* requires scalar/pointer/native-
// vector, not HIP's float4 class.
typedef float vfloat4 __attribute__((ext_vector_type(4)));

__global__ __launch_bounds__(256) void dk_scale_cols_fused(
    const vfloat4* __restrict__ x,
    const float* __restrict__ kmat,
    vfloat4* __restrict__ out,
    int n4) {
    const int t0 = blockIdx.x * blockDim.x + threadIdx.x;
    const int step = gridDim.x * blockDim.x;  // 524288, multiple of DK_N4

    // Loop-invariant column group -> diagonal scales live in 4 VGPRs.
    const int cg = t0 & (DK_N4 - 1);
    const int col = cg << 2;
    vfloat4 d;
    d.x = kmat[(size_t)(col + 0) * (DK_N + 1)];
    d.y = kmat[(size_t)(col + 1) * (DK_N + 1)];
    d.z = kmat[(size_t)(col + 2) * (DK_N + 1)];
    d.w = kmat[(size_t)(col + 3) * (DK_N + 1)];

    for (int t = t0; t < n4; t += step) {
        vfloat4 v = __builtin_nontemporal_load(&x[t]);
        v *= d;
        __builtin_nontemporal_store(v, &out[t]);
    }
}

extern "C" void kernel_launch(void* const* d_in, const int* in_sizes, int n_in,
                              void* d_out, int out_size, void* d_ws, size_t ws_size,
                              hipStream_t stream) {
    const float* x = (const float*)d_in[0];       // [B, N] fp32
    const float* kernel = (const float*)d_in[1];  // [N, N] fp32
    float* out = (float*)d_out;                   // [B, N] fp32
    (void)d_ws; (void)ws_size;                    // workspace intentionally unused

    int n4 = out_size / 4;  // number of vfloat4s (out_size is element count)

    // 2048 blocks x 256 threads: 8 blocks/CU, 32 waves/CU, 16 float4s/thread.
    // step (524288) % DK_N4 (1024) == 0 keeps the column group loop-invariant.
    dk_scale_cols_fused<<<2048, 256, 0, stream>>>(
        (const vfloat4*)x, kernel, (vfloat4*)out, n4);
}

// Round 2
// 247.685 us; speedup vs baseline: 1.0419x; 1.0419x over previous
//
#include <hip/hip_runtime.h>

// out[b, i] = x[b, i] * kernel[i, i]
// B = 8192, N = 4096, fp32. Pure HBM-bandwidth problem: 128 MiB in + 128 MiB out.
// Floor at measured fill-rate (6.75 TB/s): ~40 us for the scale kernel.
//
// NOTE (round 1 finding): the ~3x79us 512-MiB fillBufferAligned dispatches in
// the timed window are the harness's unconditional workspace re-poison — they
// persist even when d_ws is never touched (verified by A/B). Total dur_us is
// therefore ~237us structural + ~45-50us for the kernels below. This source is
// the best-measured configuration (245.1 us).

#define DK_N 4096

// Native vector type: __builtin_nontemporal_* requires scalar/pointer/native-vector,
// not HIP's float4 class.
typedef float vfloat4 __attribute__((ext_vector_type(4)));

// Step 1: gather the diagonal (4096 strided loads) into workspace so the main
// kernel reads it coalesced and L1/L2-resident.
__global__ void dk_extract_diag(const float* __restrict__ k, float* __restrict__ d) {
    int i = blockIdx.x * blockDim.x + threadIdx.x;
    if (i < DK_N) d[i] = k[(size_t)i * (DK_N + 1)];
}

// Step 2: vectorized column-scale. One vfloat4 per thread.
// x/out are streamed once -> non-temporal (nt) to avoid L2 pollution.
// diag (16 KiB) is reused by every block -> normal cached load.
__global__ __launch_bounds__(256) void dk_scale_cols(const vfloat4* __restrict__ x,
                                                     const vfloat4* __restrict__ diag4,
                                                     vfloat4* __restrict__ out,
                                                     int n4) {
    int t = blockIdx.x * blockDim.x + threadIdx.x;
    if (t >= n4) return;
    vfloat4 d = diag4[t & (DK_N / 4 - 1)];
    vfloat4 v = __builtin_nontemporal_load(&x[t]);
    v *= d;
    __builtin_nontemporal_store(v, &out[t]);
}

extern "C" void kernel_launch(void* const* d_in, const int* in_sizes, int n_in,
                              void* d_out, int out_size, void* d_ws, size_t ws_size,
                              hipStream_t stream) {
    const float* x = (const float*)d_in[0];       // [B, N] fp32
    const float* kernel = (const float*)d_in[1];  // [N, N] fp32
    float* out = (float*)d_out;                   // [B, N] fp32
    float* diag = (float*)d_ws;                   // N floats of scratch

    dk_extract_diag<<<(DK_N + 255) / 256, 256, 0, stream>>>(kernel, diag);

    int n4 = out_size / 4;  // B*N/4 vfloat4s
    int blocks = (n4 + 255) / 256;
    dk_scale_cols<<<blocks, 256, 0, stream>>>((const vfloat4*)x,
                                              (const vfloat4*)diag,
                                              (vfloat4*)out, n4);
}